// Round 14
// baseline (250.350 us; speedup 1.0000x reference)
//
#include <hip/hip_runtime.h>
#include <hip/hip_bf16.h>

#define N_NODES 50000
#define N_EDGES 800000
#define FIN 256
#define EMB 128
#define NGRAPH 256
#define TOT_E (N_EDGES + N_NODES)
#define NP 98              // partitions of 512 dst nodes (d >> 9)
#define RBLK 196           // radix blocks; 196 * 4096 edges >= 800000
#define NB 391             // buckets of 128 dst nodes

typedef __bf16 bf16;
typedef __attribute__((ext_vector_type(8))) __bf16 bf16x8;
typedef __attribute__((ext_vector_type(4))) __bf16 bf16x4;
typedef __attribute__((ext_vector_type(2))) __bf16 bf16x2;
typedef __attribute__((ext_vector_type(4))) float f32x4;
typedef __attribute__((ext_vector_type(4))) int i32x4;

// ---------------- both W transposes + f32->bf16 cast in one launch ----------------
__global__ void transpose2_kernel(const float* __restrict__ W1, bf16* __restrict__ WT1,
                                  const float* __restrict__ W2, bf16* __restrict__ WT2) {
    int t = blockIdx.x * 256 + threadIdx.x;
    if (t < FIN * EMB) {                       // WT1[c][r] = W1[r][c], r<256, c<128
        int c = t / FIN, r = t - c * FIN;
        WT1[t] = (bf16)W1[r * EMB + c];
    } else if (t < FIN * EMB + EMB * EMB) {    // WT2
        int u = t - FIN * EMB;
        int c = u / EMB, r = u - c * EMB;
        WT2[u] = (bf16)W2[r * EMB + c];
    }
}

// ---------------- CSR build (round-12 structure, confirmed write-amp ~1) ----------------
__global__ __launch_bounds__(256)
void hist_part_kernel(const int* __restrict__ e_dst, int* __restrict__ counts,
                      int* __restrict__ mat) {
    __shared__ int lh[NP];
    int t = threadIdx.x;
    for (int k = t; k < NP; k += 256) lh[k] = 0;
    __syncthreads();
    const int NQ = N_EDGES / 4;
    int base = blockIdx.x * 1024;
#pragma unroll
    for (int j = 0; j < 4; ++j) {
        int i = base + j * 256 + t;
        if (i < NQ) {
            i32x4 d4 = *(const i32x4*)(e_dst + 4 * i);
#pragma unroll
            for (int k = 0; k < 4; ++k) {
                atomicAdd(&counts[d4[k]], 1);
                atomicAdd(&lh[d4[k] >> 9], 1);
            }
        }
    }
    __syncthreads();
    for (int k = t; k < NP; k += 256) mat[k * RBLK + blockIdx.x] = lh[k];
}

__global__ __launch_bounds__(1024)
void scan_block_kernel(const int* __restrict__ counts, int* __restrict__ offsets,
                       int* __restrict__ blocksums) {
    __shared__ int lds[1024];
    int t = threadIdx.x;
    int idx = blockIdx.x * 1024 + t;
    int v = (idx < N_NODES) ? counts[idx] + 1 : 0;
    lds[t] = v;
    __syncthreads();
    for (int d = 1; d < 1024; d <<= 1) {
        int u = (t >= d) ? lds[t - d] : 0;
        __syncthreads();
        lds[t] += u;
        __syncthreads();
    }
    if (idx < N_NODES) offsets[idx] = lds[t] - v;
    if (t == 1023) blocksums[blockIdx.x] = lds[1023];
}

__global__ __launch_bounds__(1024)
void scan_fix_kernel(int* __restrict__ offsets, const int* __restrict__ blocksums,
                     int nblk, int* __restrict__ sorted) {
    __shared__ int sprefix;
    int t = threadIdx.x, b = blockIdx.x;
    if (t < 64) {
        int v = (t < b && t < nblk) ? blocksums[t] : 0;
#pragma unroll
        for (int mk = 32; mk >= 1; mk >>= 1) v += __shfl_xor(v, mk);
        if (t == 0) sprefix = v;
    }
    __syncthreads();
    int idx = b * 1024 + t;
    if (idx < N_NODES) {
        int off = offsets[idx] + sprefix;
        offsets[idx] = off;
        sorted[off] = idx;          // self-loop at slot 0
    }
    if (idx == 0) offsets[N_NODES] = TOT_E;
}

__global__ __launch_bounds__(256)
void rowscan_kernel(int* __restrict__ mat, int* __restrict__ rowsum) {
    __shared__ int lds[256];
    int p = blockIdx.x, t = threadIdx.x;
    int v = (t < RBLK) ? mat[p * RBLK + t] : 0;
    lds[t] = v;
    __syncthreads();
    for (int d = 1; d < 256; d <<= 1) {
        int u = (t >= d) ? lds[t - d] : 0;
        __syncthreads();
        lds[t] += u;
        __syncthreads();
    }
    if (t < RBLK) mat[p * RBLK + t] = lds[t] - v;
    if (t == 255) rowsum[p] = lds[255];
}

__global__ __launch_bounds__(128)
void partbase_kernel(const int* __restrict__ rowsum, int* __restrict__ poff) {
    __shared__ int lds[128];
    int t = threadIdx.x;
    int v = (t < NP) ? rowsum[t] : 0;
    lds[t] = v;
    __syncthreads();
    for (int d = 1; d < 128; d <<= 1) {
        int u = (t >= d) ? lds[t - d] : 0;
        __syncthreads();
        lds[t] += u;
        __syncthreads();
    }
    if (t < NP) poff[t] = lds[t] - v;
    if (t == 0) poff[NP] = N_EDGES;
}

__global__ __launch_bounds__(256)
void radix_scatter_kernel(const int* __restrict__ e_src, const int* __restrict__ e_dst,
                          const int* __restrict__ mat, const int* __restrict__ poff,
                          unsigned* __restrict__ pairs) {
    __shared__ int cur[NP];
    int t = threadIdx.x;
    for (int k = t; k < NP; k += 256) cur[k] = poff[k] + mat[k * RBLK + blockIdx.x];
    __syncthreads();
    const int NQ = N_EDGES / 4;
    int base = blockIdx.x * 1024;
#pragma unroll
    for (int j = 0; j < 4; ++j) {
        int i = base + j * 256 + t;
        if (i < NQ) {
            i32x4 d4 = *(const i32x4*)(e_dst + 4 * i);
            i32x4 s4 = *(const i32x4*)(e_src + 4 * i);
#pragma unroll
            for (int k = 0; k < 4; ++k) {
                int d = d4[k];
                int pos = atomicAdd(&cur[d >> 9], 1);
                pairs[pos] = ((unsigned)d << 16) | (unsigned)s4[k];
            }
        }
    }
}

__global__ __launch_bounds__(1024)
void bucket_place_kernel(const int* __restrict__ poff, const int* __restrict__ offsets,
                         const unsigned* __restrict__ pairs, int* __restrict__ sorted) {
    int b = blockIdx.x;
    int t = threadIdx.x;
    int lo = b * 128;
    __shared__ int cur[128];
    if (t < 128 && lo + t < N_NODES) cur[t] = offsets[lo + t] + 1;
    __syncthreads();
    int p = b >> 2;
    int p0 = poff[p], p1 = poff[p + 1];
    unsigned blo = (unsigned)b;
    for (int i = p0 + t; i < p1; i += 1024) {
        unsigned v = pairs[i];
        unsigned d = v >> 16;
        if ((d >> 7) == blo) {
            int pos = atomicAdd(&cur[d & 127], 1);
            sorted[pos] = (int)(v & 0xFFFFu);
        }
    }
}

// ---------------- GEMM + fused scores (round-14: no-LDS, direct-register) --------
// N=128 -> a wave's A-fragment is wave-private and register-reused across all 8
// column fragments; WT is <=64KB and L1/L2-hot. So LDS staging bought nothing and
// cost 2 barriers + a VGPR->LDS->VGPR round trip per K-step (r13 gained <20%).
// Now: lanes {l,l+16,l+32,l+48} cover one row's contiguous 64B(bf16)/128B(f32)
// per fragment -> full-line coalescing; no barriers; no LDS.
template<int K, typename AT>
__global__ __launch_bounds__(256)
void gemm_kernel(const AT* __restrict__ A, const bf16* __restrict__ WT,
                 bf16* __restrict__ C, int M,
                 const float* __restrict__ a_src, const float* __restrict__ a_dst,
                 float* __restrict__ s_src, float* __restrict__ s_dst) {
    int tid = threadIdx.x;
    int wave = tid >> 6, lane = tid & 63;
    int m0 = blockIdx.x * 64;
    int r = m0 + wave * 16 + (lane & 15);
    int kseg = lane >> 4;                    // 0..3
    bool rok = r < M;

    f32x4 acc[8];
#pragma unroll
    for (int i = 0; i < 8; ++i) acc[i] = (f32x4){0.f, 0.f, 0.f, 0.f};

    for (int k0 = 0; k0 < K; k0 += 64) {
        bf16x8 af0, af1;
        if constexpr (sizeof(AT) == 4) {
            const float* ap = (const float*)A + (size_t)r * K + k0 + kseg * 8;
            float4 f0 = make_float4(0.f, 0.f, 0.f, 0.f), f1 = f0, f2 = f0, f3 = f0;
            if (rok) {
                f0 = *(const float4*)(ap);
                f1 = *(const float4*)(ap + 4);
                f2 = *(const float4*)(ap + 32);
                f3 = *(const float4*)(ap + 36);
            }
            af0 = (bf16x8){(bf16)f0.x, (bf16)f0.y, (bf16)f0.z, (bf16)f0.w,
                           (bf16)f1.x, (bf16)f1.y, (bf16)f1.z, (bf16)f1.w};
            af1 = (bf16x8){(bf16)f2.x, (bf16)f2.y, (bf16)f2.z, (bf16)f2.w,
                           (bf16)f3.x, (bf16)f3.y, (bf16)f3.z, (bf16)f3.w};
        } else {
            const bf16* ap = (const bf16*)A + (size_t)r * K + k0 + kseg * 8;
            af0 = rok ? *(const bf16x8*)(ap)      : (bf16x8){0, 0, 0, 0, 0, 0, 0, 0};
            af1 = rok ? *(const bf16x8*)(ap + 32) : (bf16x8){0, 0, 0, 0, 0, 0, 0, 0};
        }
#pragma unroll
        for (int n = 0; n < 8; ++n) {
            int c = n * 16 + (lane & 15);
            const bf16* bp = WT + (size_t)c * K + k0 + kseg * 8;
            bf16x8 b0 = *(const bf16x8*)(bp);
            bf16x8 b1 = *(const bf16x8*)(bp + 32);
            acc[n] = __builtin_amdgcn_mfma_f32_16x16x32_bf16(af0, b0, acc[n], 0, 0, 0);
            acc[n] = __builtin_amdgcn_mfma_f32_16x16x32_bf16(af1, b1, acc[n], 0, 0, 0);
        }
    }
    int rbase = m0 + wave * 16 + ((lane >> 4) << 2);
    int cbase = lane & 15;
#pragma unroll
    for (int n = 0; n < 8; ++n) {
#pragma unroll
        for (int rr = 0; rr < 4; ++rr) {
            int row = rbase + rr;
            if (row < M) C[(size_t)row * 128 + n * 16 + cbase] = (bf16)acc[n][rr];
        }
    }
    // fused scores epilogue
    float a_s[8], a_d[8];
#pragma unroll
    for (int n = 0; n < 8; ++n) {
        a_s[n] = a_src[n * 16 + cbase];
        a_d[n] = a_dst[n * 16 + cbase];
    }
#pragma unroll
    for (int rr = 0; rr < 4; ++rr) {
        float ps = 0.f, pd = 0.f;
#pragma unroll
        for (int n = 0; n < 8; ++n) {
            ps += acc[n][rr] * a_s[n];
            pd += acc[n][rr] * a_d[n];
        }
#pragma unroll
        for (int mk = 8; mk >= 1; mk >>= 1) {
            ps += __shfl_xor(ps, mk);
            pd += __shfl_xor(pd, mk);
        }
        int row = rbase + rr;
        if (cbase == 0 && row < M) { s_src[row] = ps; s_dst[row] = pd; }
    }
}

// ---------------- per-node softmax-aggregate (16-lane groups, 4 nodes/wave) ----------------
template<typename OUT_T>
__global__ __launch_bounds__(256)
void agg_kernel(const int* __restrict__ offsets, const int* __restrict__ sorted_src,
                const float* __restrict__ s_src, const float* __restrict__ s_dst,
                const bf16* __restrict__ h, const float* __restrict__ bias,
                OUT_T* __restrict__ out) {
    int tid = threadIdx.x;
    int wave = tid >> 6, lane = tid & 63;
    int gl = lane & 15;
    int gbase = lane & 48;
    int d = blockIdx.x * 16 + wave * 4 + (lane >> 4);
    if (d >= N_NODES) return;
    int r0 = offsets[d];
    int deg = offsets[d + 1] - r0;
    float sd = s_dst[d];

    int sv0 = 0, sv1 = 0;
    float ev0 = -INFINITY, ev1 = -INFINITY;
    if (gl < deg) {
        sv0 = sorted_src[r0 + gl];
        float e = s_src[sv0] + sd;
        ev0 = (e > 0.f) ? e : 0.2f * e;
    }
    if (16 + gl < deg) {
        sv1 = sorted_src[r0 + 16 + gl];
        float e = s_src[sv1] + sd;
        ev1 = (e > 0.f) ? e : 0.2f * e;
    }
    float m = fmaxf(ev0, ev1);
    for (int i = 32 + gl; i < deg; i += 16) {
        int s = sorted_src[r0 + i];
        float e = s_src[s] + sd;
        e = (e > 0.f) ? e : 0.2f * e;
        m = fmaxf(m, e);
    }
#pragma unroll
    for (int mk = 8; mk >= 1; mk >>= 1) m = fmaxf(m, __shfl_xor(m, mk));

    float pv0 = (gl < deg) ? __expf(ev0 - m) : 0.f;
    float pv1 = (16 + gl < deg) ? __expf(ev1 - m) : 0.f;
    float den = pv0 + pv1;
    for (int i = 32 + gl; i < deg; i += 16) {
        int s = sorted_src[r0 + i];
        float e = s_src[s] + sd;
        e = (e > 0.f) ? e : 0.2f * e;
        den += __expf(e - m);
    }
#pragma unroll
    for (int mk = 8; mk >= 1; mk >>= 1) den += __shfl_xor(den, mk);

    float acc[8];
#pragma unroll
    for (int k = 0; k < 8; ++k) acc[k] = 0.f;

    int jm = (deg < 32) ? deg : 32;
#pragma unroll 8
    for (int j = 0; j < jm; ++j) {
        int src_lane = gbase + (j & 15);
        int s = __shfl((j < 16) ? sv0 : sv1, src_lane);
        float p = __shfl((j < 16) ? pv0 : pv1, src_lane);
        bf16x8 hv = *(const bf16x8*)(h + (size_t)s * 128 + gl * 8);
#pragma unroll
        for (int k = 0; k < 8; ++k) acc[k] += p * (float)hv[k];
    }
    for (int i = 32; i < deg; ++i) {
        int s = sorted_src[r0 + i];
        float e = s_src[s] + sd;
        e = (e > 0.f) ? e : 0.2f * e;
        float p = __expf(e - m);
        bf16x8 hv = *(const bf16x8*)(h + (size_t)s * 128 + gl * 8);
#pragma unroll
        for (int k = 0; k < 8; ++k) acc[k] += p * (float)hv[k];
    }

    float inv = 1.f / den;
    float4 bv0 = *(const float4*)(bias + gl * 8);
    float4 bv1 = *(const float4*)(bias + gl * 8 + 4);
    float o[8] = {acc[0] * inv + bv0.x, acc[1] * inv + bv0.y,
                  acc[2] * inv + bv0.z, acc[3] * inv + bv0.w,
                  acc[4] * inv + bv1.x, acc[5] * inv + bv1.y,
                  acc[6] * inv + bv1.z, acc[7] * inv + bv1.w};
    if constexpr (sizeof(OUT_T) == 2) {
        bf16x8 ov;
#pragma unroll
        for (int k = 0; k < 8; ++k) ov[k] = (bf16)o[k];
        *(bf16x8*)((bf16*)out + (size_t)d * 128 + gl * 8) = ov;
    } else {
        float* op = (float*)out + (size_t)d * 128 + gl * 8;
        *(float4*)op       = (float4){o[0], o[1], o[2], o[3]};
        *(float4*)(op + 4) = (float4){o[4], o[5], o[6], o[7]};
    }
}

// ---------------- per-graph mean/max pooling (bf16 input; batch_idx sorted) -------
__global__ __launch_bounds__(256)
void pool_kernel(const bf16* __restrict__ out2, const int* __restrict__ batch_idx,
                 float* __restrict__ mean, float* __restrict__ mx) {
    int g = blockIdx.x;
    int j = threadIdx.x & 127;
    int grp = threadIdx.x >> 7;
    int lo = 0, hi = N_NODES;
    while (lo < hi) { int mid = (lo + hi) >> 1; if (batch_idx[mid] < g) lo = mid + 1; else hi = mid; }
    int start = lo;
    hi = N_NODES;
    while (lo < hi) { int mid = (lo + hi) >> 1; if (batch_idx[mid] < g + 1) lo = mid + 1; else hi = mid; }
    int end = lo;

    float s = 0.f, mmax = -INFINITY;
    for (int r = start + grp; r < end; r += 2) {
        float v = (float)out2[(size_t)r * 128 + j];
        s += v;
        mmax = fmaxf(mmax, v);
    }
    __shared__ float ls[2][128], lm[2][128];
    ls[grp][j] = s; lm[grp][j] = mmax;
    __syncthreads();
    if (grp == 0) {
        int cnt = end - start;
        float sum = ls[0][j] + ls[1][j];
        float mv = fmaxf(lm[0][j], lm[1][j]);
        mean[g * 128 + j] = sum / fmaxf((float)cnt, 1.f);
        mx[g * 128 + j] = (cnt > 0) ? mv : 0.f;
    }
}

// ---------------- head ----------------
__global__ __launch_bounds__(128)
void head_kernel(const float* __restrict__ mean, const float* __restrict__ mx,
                 const float* __restrict__ gfeat, const float* __restrict__ Wg,
                 const float* __restrict__ bg, const float* __restrict__ Wo,
                 const float* __restrict__ bo, float* __restrict__ out) {
    int g = blockIdx.x;
    int j = threadIdx.x;
    float gft = bg[j];
#pragma unroll
    for (int k = 0; k < 32; ++k)
        gft += gfeat[g * 32 + k] * Wg[k * 128 + j];
    float mj = mean[g * 128 + j], xj = mx[g * 128 + j];
    float p0 = mj * Wo[j * 2 + 0] + xj * Wo[(128 + j) * 2 + 0] + gft * Wo[(256 + j) * 2 + 0];
    float p1 = mj * Wo[j * 2 + 1] + xj * Wo[(128 + j) * 2 + 1] + gft * Wo[(256 + j) * 2 + 1];
#pragma unroll
    for (int m = 32; m >= 1; m >>= 1) { p0 += __shfl_xor(p0, m); p1 += __shfl_xor(p1, m); }
    __shared__ float l0s[2], l1s[2];
    int wv = j >> 6;
    if ((j & 63) == 0) { l0s[wv] = p0; l1s[wv] = p1; }
    __syncthreads();
    if (j == 0) {
        float l0 = l0s[0] + l0s[1] + bo[0];
        float l1 = l1s[0] + l1s[1] + bo[1];
        float mm = fmaxf(l0, l1);
        float lse = mm + logf(__expf(l0 - mm) + __expf(l1 - mm));
        out[g * 2 + 0] = l0 - lse;
        out[g * 2 + 1] = l1 - lse;
    }
}

extern "C" void kernel_launch(void* const* d_in, const int* in_sizes, int n_in,
                              void* d_out, int out_size, void* d_ws, size_t ws_size,
                              hipStream_t stream) {
    const float* x     = (const float*)d_in[0];
    const int*   edges = (const int*)d_in[1];
    const int*   batch = (const int*)d_in[2];
    const float* gfeat = (const float*)d_in[3];
    const float* W1    = (const float*)d_in[4];
    const float* a1s   = (const float*)d_in[5];
    const float* a1d   = (const float*)d_in[6];
    const float* b1    = (const float*)d_in[7];
    const float* W2    = (const float*)d_in[8];
    const float* a2s   = (const float*)d_in[9];
    const float* a2d   = (const float*)d_in[10];
    const float* b2    = (const float*)d_in[11];
    const float* Wg    = (const float*)d_in[12];
    const float* bg    = (const float*)d_in[13];
    const float* Wo    = (const float*)d_in[14];
    const float* bo    = (const float*)d_in[15];

    char* ws = (char*)d_ws;
    bf16*     WT1       = (bf16*)(ws + 0);          //  65536 B
    bf16*     WT2       = (bf16*)(ws + 65536);      //  32768 B
    float*    s_src     = (float*)(ws + 98304);     // 200704 B
    float*    s_dst     = (float*)(ws + 299008);    // 200704 B
    int*      counts    = (int*)(ws + 499712);      // 200704 B
    int*      blocksums = (int*)(ws + 700416);      // 256 B
    int*      mat       = (int*)(ws + 700672);      // 76832 B
    int*      rowsum    = (int*)(ws + 777536);      // 392 B
    int*      poff      = (int*)(ws + 777984);      // 396 B
    int*      offsets   = (int*)(ws + 778432);      // 200704 B (N+1 ints)
    int*      sorted    = (int*)(ws + 979136);      // 3400704 B
    bf16*     h         = (bf16*)(ws + 4502528);    // 12.8 MB
    bf16*     out1      = (bf16*)(ws + 17302528);   // 12.8 MB
    bf16*     out2      = (bf16*)(ws + 30102528);   // 12.8 MB
    unsigned* pairs     = (unsigned*)(ws + 43002528); // 3.2 MB
    float*    pmean     = (float*)(ws + 55702528);  // 131072 B
    float*    pmax      = (float*)(ws + 55833600);  // 131072 B

    const int* e_src = edges;
    const int* e_dst = edges + N_EDGES;

    // --- W transposes + f32->bf16 cast (single tiny launch) ---
    transpose2_kernel<<<(FIN * EMB + EMB * EMB + 255) / 256, 256, 0, stream>>>(W1, WT1, W2, WT2);

    // --- CSR by dst: fine radix partition (98), single-writer write lines ---
    hipMemsetAsync(counts, 0, N_NODES * sizeof(int), stream);
    hist_part_kernel<<<RBLK, 256, 0, stream>>>(e_dst, counts, mat);
    int nblk = (N_NODES + 1023) / 1024;   // 49
    scan_block_kernel<<<nblk, 1024, 0, stream>>>(counts, offsets, blocksums);
    scan_fix_kernel<<<nblk, 1024, 0, stream>>>(offsets, blocksums, nblk, sorted);
    rowscan_kernel<<<NP, 256, 0, stream>>>(mat, rowsum);
    partbase_kernel<<<1, 128, 0, stream>>>(rowsum, poff);
    radix_scatter_kernel<<<RBLK, 256, 0, stream>>>(e_src, e_dst, mat, poff, pairs);
    bucket_place_kernel<<<NB, 1024, 0, stream>>>(poff, offsets, pairs, sorted);

    int gemm_blocks = (N_NODES + 63) / 64;
    int agg_blocks = (N_NODES + 15) / 16;

    // --- layer 1 (scores fused into gemm epilogue) ---
    gemm_kernel<FIN, float><<<gemm_blocks, 256, 0, stream>>>(x, WT1, h, N_NODES,
                                                             a1s, a1d, s_src, s_dst);
    agg_kernel<bf16><<<agg_blocks, 256, 0, stream>>>(offsets, sorted, s_src, s_dst, h, b1, out1);

    // --- layer 2 ---
    gemm_kernel<EMB, bf16><<<gemm_blocks, 256, 0, stream>>>(out1, WT2, h, N_NODES,
                                                            a2s, a2d, s_src, s_dst);
    agg_kernel<bf16><<<agg_blocks, 256, 0, stream>>>(offsets, sorted, s_src, s_dst, h, b2, out2);

    // --- pooling + head ---
    pool_kernel<<<NGRAPH, 256, 0, stream>>>(out2, batch, pmean, pmax);
    head_kernel<<<NGRAPH, 128, 0, stream>>>(pmean, pmax, gfeat, Wg, bg, Wo, bo, (float*)d_out);
}

// Round 15
// 213.906 us; speedup vs baseline: 1.1704x; 1.1704x over previous
//
#include <hip/hip_runtime.h>
#include <hip/hip_bf16.h>

#define N_NODES 50000
#define N_EDGES 800000
#define FIN 256
#define EMB 128
#define NGRAPH 256
#define TOT_E (N_EDGES + N_NODES)
#define NP 98              // partitions of 512 dst nodes (d >> 9)
#define RBLK 196           // radix blocks; 196 * 4096 edges >= 800000
#define NB 391             // buckets of 128 dst nodes

typedef __bf16 bf16;
typedef __attribute__((ext_vector_type(8))) __bf16 bf16x8;
typedef __attribute__((ext_vector_type(4))) __bf16 bf16x4;
typedef __attribute__((ext_vector_type(2))) __bf16 bf16x2;
typedef __attribute__((ext_vector_type(4))) float f32x4;
typedef __attribute__((ext_vector_type(4))) int i32x4;

// ---------------- both W transposes + f32->bf16 cast in one launch ----------------
__global__ void transpose2_kernel(const float* __restrict__ W1, bf16* __restrict__ WT1,
                                  const float* __restrict__ W2, bf16* __restrict__ WT2) {
    int t = blockIdx.x * 256 + threadIdx.x;
    if (t < FIN * EMB) {                       // WT1[c][r] = W1[r][c], r<256, c<128
        int c = t / FIN, r = t - c * FIN;
        WT1[t] = (bf16)W1[r * EMB + c];
    } else if (t < FIN * EMB + EMB * EMB) {    // WT2
        int u = t - FIN * EMB;
        int c = u / EMB, r = u - c * EMB;
        WT2[u] = (bf16)W2[r * EMB + c];
    }
}

// ---------------- CSR build (round-12 structure, confirmed write-amp ~1) ----------------
__global__ __launch_bounds__(256)
void hist_part_kernel(const int* __restrict__ e_dst, int* __restrict__ counts,
                      int* __restrict__ mat) {
    __shared__ int lh[NP];
    int t = threadIdx.x;
    for (int k = t; k < NP; k += 256) lh[k] = 0;
    __syncthreads();
    const int NQ = N_EDGES / 4;
    int base = blockIdx.x * 1024;
#pragma unroll
    for (int j = 0; j < 4; ++j) {
        int i = base + j * 256 + t;
        if (i < NQ) {
            i32x4 d4 = *(const i32x4*)(e_dst + 4 * i);
#pragma unroll
            for (int k = 0; k < 4; ++k) {
                atomicAdd(&counts[d4[k]], 1);
                atomicAdd(&lh[d4[k] >> 9], 1);
            }
        }
    }
    __syncthreads();
    for (int k = t; k < NP; k += 256) mat[k * RBLK + blockIdx.x] = lh[k];
}

__global__ __launch_bounds__(1024)
void scan_block_kernel(const int* __restrict__ counts, int* __restrict__ offsets,
                       int* __restrict__ blocksums) {
    __shared__ int lds[1024];
    int t = threadIdx.x;
    int idx = blockIdx.x * 1024 + t;
    int v = (idx < N_NODES) ? counts[idx] + 1 : 0;
    lds[t] = v;
    __syncthreads();
    for (int d = 1; d < 1024; d <<= 1) {
        int u = (t >= d) ? lds[t - d] : 0;
        __syncthreads();
        lds[t] += u;
        __syncthreads();
    }
    if (idx < N_NODES) offsets[idx] = lds[t] - v;
    if (t == 1023) blocksums[blockIdx.x] = lds[1023];
}

__global__ __launch_bounds__(1024)
void scan_fix_kernel(int* __restrict__ offsets, const int* __restrict__ blocksums,
                     int nblk, int* __restrict__ sorted) {
    __shared__ int sprefix;
    int t = threadIdx.x, b = blockIdx.x;
    if (t < 64) {
        int v = (t < b && t < nblk) ? blocksums[t] : 0;
#pragma unroll
        for (int mk = 32; mk >= 1; mk >>= 1) v += __shfl_xor(v, mk);
        if (t == 0) sprefix = v;
    }
    __syncthreads();
    int idx = b * 1024 + t;
    if (idx < N_NODES) {
        int off = offsets[idx] + sprefix;
        offsets[idx] = off;
        sorted[off] = idx;          // self-loop at slot 0
    }
    if (idx == 0) offsets[N_NODES] = TOT_E;
}

__global__ __launch_bounds__(256)
void rowscan_kernel(int* __restrict__ mat, int* __restrict__ rowsum) {
    __shared__ int lds[256];
    int p = blockIdx.x, t = threadIdx.x;
    int v = (t < RBLK) ? mat[p * RBLK + t] : 0;
    lds[t] = v;
    __syncthreads();
    for (int d = 1; d < 256; d <<= 1) {
        int u = (t >= d) ? lds[t - d] : 0;
        __syncthreads();
        lds[t] += u;
        __syncthreads();
    }
    if (t < RBLK) mat[p * RBLK + t] = lds[t] - v;
    if (t == 255) rowsum[p] = lds[255];
}

__global__ __launch_bounds__(128)
void partbase_kernel(const int* __restrict__ rowsum, int* __restrict__ poff) {
    __shared__ int lds[128];
    int t = threadIdx.x;
    int v = (t < NP) ? rowsum[t] : 0;
    lds[t] = v;
    __syncthreads();
    for (int d = 1; d < 128; d <<= 1) {
        int u = (t >= d) ? lds[t - d] : 0;
        __syncthreads();
        lds[t] += u;
        __syncthreads();
    }
    if (t < NP) poff[t] = lds[t] - v;
    if (t == 0) poff[NP] = N_EDGES;
}

__global__ __launch_bounds__(256)
void radix_scatter_kernel(const int* __restrict__ e_src, const int* __restrict__ e_dst,
                          const int* __restrict__ mat, const int* __restrict__ poff,
                          unsigned* __restrict__ pairs) {
    __shared__ int cur[NP];
    int t = threadIdx.x;
    for (int k = t; k < NP; k += 256) cur[k] = poff[k] + mat[k * RBLK + blockIdx.x];
    __syncthreads();
    const int NQ = N_EDGES / 4;
    int base = blockIdx.x * 1024;
#pragma unroll
    for (int j = 0; j < 4; ++j) {
        int i = base + j * 256 + t;
        if (i < NQ) {
            i32x4 d4 = *(const i32x4*)(e_dst + 4 * i);
            i32x4 s4 = *(const i32x4*)(e_src + 4 * i);
#pragma unroll
            for (int k = 0; k < 4; ++k) {
                int d = d4[k];
                int pos = atomicAdd(&cur[d >> 9], 1);
                pairs[pos] = ((unsigned)d << 16) | (unsigned)s4[k];
            }
        }
    }
}

__global__ __launch_bounds__(1024)
void bucket_place_kernel(const int* __restrict__ poff, const int* __restrict__ offsets,
                         const unsigned* __restrict__ pairs, int* __restrict__ sorted) {
    int b = blockIdx.x;
    int t = threadIdx.x;
    int lo = b * 128;
    __shared__ int cur[128];
    if (t < 128 && lo + t < N_NODES) cur[t] = offsets[lo + t] + 1;
    __syncthreads();
    int p = b >> 2;
    int p0 = poff[p], p1 = poff[p + 1];
    unsigned blo = (unsigned)b;
    for (int i = p0 + t; i < p1; i += 1024) {
        unsigned v = pairs[i];
        unsigned d = v >> 16;
        if ((d >> 7) == blo) {
            int pos = atomicAdd(&cur[d & 127], 1);
            sorted[pos] = (int)(v & 0xFFFFu);
        }
    }
}

// ---------------- GEMM + fused scores (round-15: LDS r13 structure, 32-row tile) --
// r14 de-LDS regressed (50us, MfmaUtil 2%, occ 22%: latency-bound, no TLP). Revert
// to LDS staging (BK=64 + XOR swizzle, r13) but HALVE the tile to 32 rows: grid
// 782->1563 blocks = 3->6 blocks/CU = 24 waves/CU, doubling the wave-level overlap
// that hides staging latency. Wave w: rows (w&1)*16..+16, cols (w>>1)*64..+64.
// Scores epilogue combines the two col-half waves via a tiny LDS buffer.
template<int K, typename AT>
__global__ __launch_bounds__(256)
void gemm_kernel(const AT* __restrict__ A, const bf16* __restrict__ WT,
                 bf16* __restrict__ C, int M,
                 const float* __restrict__ a_src, const float* __restrict__ a_dst,
                 float* __restrict__ s_src, float* __restrict__ s_dst) {
    __shared__ __align__(16) bf16 As[32][64];    //  4 KB
    __shared__ __align__(16) bf16 Bs[128][64];   // 16 KB
    __shared__ float sbuf[2][32];
    int tid = threadIdx.x;
    int wave = tid >> 6, lane = tid & 63;
    int rowHalf = wave & 1, colHalf = wave >> 1;
    int m0 = blockIdx.x * 32;

    f32x4 acc[4];
#pragma unroll
    for (int i = 0; i < 4; ++i) acc[i] = (f32x4){0.f, 0.f, 0.f, 0.f};

    for (int k0 = 0; k0 < K; k0 += 64) {
        // ---- stage A[32][64] (convert f32->bf16 on the fly if needed) ----
        if constexpr (sizeof(AT) == 4) {
#pragma unroll
            for (int it = 0; it < 2; ++it) {               // 32 rows x 16 seg4
                int task = tid + it * 256;
                int row = task >> 4, seg4 = task & 15;
                int gr = m0 + row;
                float4 f = make_float4(0.f, 0.f, 0.f, 0.f);
                if (gr < M) f = *(const float4*)((const float*)A + (size_t)gr * K + k0 + seg4 * 4);
                bf16x4 b4 = (bf16x4){(bf16)f.x, (bf16)f.y, (bf16)f.z, (bf16)f.w};
                int slot = seg4 >> 1, half8 = seg4 & 1;
                int ss = slot ^ (row & 7);
                *(bf16x4*)(&As[row][ss * 8 + half8 * 4]) = b4;
            }
        } else {
            int row = tid >> 3, slot = tid & 7;            // 32 rows x 8 slots
            int gr = m0 + row;
            uint4 v = make_uint4(0u, 0u, 0u, 0u);
            if (gr < M) v = *(const uint4*)((const bf16*)A + (size_t)gr * K + k0 + slot * 8);
            int ss = slot ^ (row & 7);
            *(uint4*)(&As[row][ss * 8]) = v;
        }
        // ---- stage B^T[128][64] from WT[128][K] ----
#pragma unroll
        for (int it = 0; it < 4; ++it) {                   // 128 cols x 8 slots
            int task = tid + it * 256;
            int col = task >> 3, slot = task & 7;
            uint4 v = *(const uint4*)(WT + (size_t)col * K + k0 + slot * 8);
            int ss = slot ^ (col & 7);
            *(uint4*)(&Bs[col][ss * 8]) = v;
        }
        __syncthreads();
        // ---- 8 MFMAs per wave (2 K-halves x 4 col-fragments) ----
        int tr = rowHalf * 16 + (lane & 15);
        int kseg = lane >> 4;                              // 0..3
        bf16x8 af0 = *(const bf16x8*)(&As[tr][((kseg) ^ (tr & 7)) * 8]);
        bf16x8 af1 = *(const bf16x8*)(&As[tr][((4 + kseg) ^ (tr & 7)) * 8]);
#pragma unroll
        for (int n = 0; n < 4; ++n) {
            int c = colHalf * 64 + n * 16 + (lane & 15);
            bf16x8 b0 = *(const bf16x8*)(&Bs[c][((kseg) ^ (c & 7)) * 8]);
            bf16x8 b1 = *(const bf16x8*)(&Bs[c][((4 + kseg) ^ (c & 7)) * 8]);
            acc[n] = __builtin_amdgcn_mfma_f32_16x16x32_bf16(af0, b0, acc[n], 0, 0, 0);
            acc[n] = __builtin_amdgcn_mfma_f32_16x16x32_bf16(af1, b1, acc[n], 0, 0, 0);
        }
        __syncthreads();
    }
    // ---- C write ----
    int rbase = m0 + rowHalf * 16 + ((lane >> 4) << 2);
    int cb = lane & 15;
#pragma unroll
    for (int n = 0; n < 4; ++n) {
        int col = colHalf * 64 + n * 16 + cb;
#pragma unroll
        for (int rr = 0; rr < 4; ++rr) {
            int row = rbase + rr;
            if (row < M) C[(size_t)row * 128 + col] = (bf16)acc[n][rr];
        }
    }
    // ---- fused scores epilogue (cross col-half combine via LDS) ----
    if (tid < 64) sbuf[tid >> 5][tid & 31] = 0.f;
    __syncthreads();
    float a_s[4], a_d[4];
#pragma unroll
    for (int n = 0; n < 4; ++n) {
        a_s[n] = a_src[colHalf * 64 + n * 16 + cb];
        a_d[n] = a_dst[colHalf * 64 + n * 16 + cb];
    }
#pragma unroll
    for (int rr = 0; rr < 4; ++rr) {
        float ps = 0.f, pd = 0.f;
#pragma unroll
        for (int n = 0; n < 4; ++n) {
            ps += acc[n][rr] * a_s[n];
            pd += acc[n][rr] * a_d[n];
        }
#pragma unroll
        for (int mk = 8; mk >= 1; mk >>= 1) {
            ps += __shfl_xor(ps, mk);
            pd += __shfl_xor(pd, mk);
        }
        if (cb == 0) {
            int tr16 = rowHalf * 16 + (lane >> 4) * 4 + rr;
            atomicAdd(&sbuf[0][tr16], ps);
            atomicAdd(&sbuf[1][tr16], pd);
        }
    }
    __syncthreads();
    if (tid < 32 && m0 + tid < M) {
        s_src[m0 + tid] = sbuf[0][tid];
        s_dst[m0 + tid] = sbuf[1][tid];
    }
}

// ---------------- per-node softmax-aggregate (16-lane groups, 4 nodes/wave) ----------------
template<typename OUT_T>
__global__ __launch_bounds__(256)
void agg_kernel(const int* __restrict__ offsets, const int* __restrict__ sorted_src,
                const float* __restrict__ s_src, const float* __restrict__ s_dst,
                const bf16* __restrict__ h, const float* __restrict__ bias,
                OUT_T* __restrict__ out) {
    int tid = threadIdx.x;
    int wave = tid >> 6, lane = tid & 63;
    int gl = lane & 15;
    int gbase = lane & 48;
    int d = blockIdx.x * 16 + wave * 4 + (lane >> 4);
    if (d >= N_NODES) return;
    int r0 = offsets[d];
    int deg = offsets[d + 1] - r0;
    float sd = s_dst[d];

    int sv0 = 0, sv1 = 0;
    float ev0 = -INFINITY, ev1 = -INFINITY;
    if (gl < deg) {
        sv0 = sorted_src[r0 + gl];
        float e = s_src[sv0] + sd;
        ev0 = (e > 0.f) ? e : 0.2f * e;
    }
    if (16 + gl < deg) {
        sv1 = sorted_src[r0 + 16 + gl];
        float e = s_src[sv1] + sd;
        ev1 = (e > 0.f) ? e : 0.2f * e;
    }
    float m = fmaxf(ev0, ev1);
    for (int i = 32 + gl; i < deg; i += 16) {
        int s = sorted_src[r0 + i];
        float e = s_src[s] + sd;
        e = (e > 0.f) ? e : 0.2f * e;
        m = fmaxf(m, e);
    }
#pragma unroll
    for (int mk = 8; mk >= 1; mk >>= 1) m = fmaxf(m, __shfl_xor(m, mk));

    float pv0 = (gl < deg) ? __expf(ev0 - m) : 0.f;
    float pv1 = (16 + gl < deg) ? __expf(ev1 - m) : 0.f;
    float den = pv0 + pv1;
    for (int i = 32 + gl; i < deg; i += 16) {
        int s = sorted_src[r0 + i];
        float e = s_src[s] + sd;
        e = (e > 0.f) ? e : 0.2f * e;
        den += __expf(e - m);
    }
#pragma unroll
    for (int mk = 8; mk >= 1; mk >>= 1) den += __shfl_xor(den, mk);

    float acc[8];
#pragma unroll
    for (int k = 0; k < 8; ++k) acc[k] = 0.f;

    int jm = (deg < 32) ? deg : 32;
#pragma unroll 8
    for (int j = 0; j < jm; ++j) {
        int src_lane = gbase + (j & 15);
        int s = __shfl((j < 16) ? sv0 : sv1, src_lane);
        float p = __shfl((j < 16) ? pv0 : pv1, src_lane);
        bf16x8 hv = *(const bf16x8*)(h + (size_t)s * 128 + gl * 8);
#pragma unroll
        for (int k = 0; k < 8; ++k) acc[k] += p * (float)hv[k];
    }
    for (int i = 32; i < deg; ++i) {
        int s = sorted_src[r0 + i];
        float e = s_src[s] + sd;
        e = (e > 0.f) ? e : 0.2f * e;
        float p = __expf(e - m);
        bf16x8 hv = *(const bf16x8*)(h + (size_t)s * 128 + gl * 8);
#pragma unroll
        for (int k = 0; k < 8; ++k) acc[k] += p * (float)hv[k];
    }

    float inv = 1.f / den;
    float4 bv0 = *(const float4*)(bias + gl * 8);
    float4 bv1 = *(const float4*)(bias + gl * 8 + 4);
    float o[8] = {acc[0] * inv + bv0.x, acc[1] * inv + bv0.y,
                  acc[2] * inv + bv0.z, acc[3] * inv + bv0.w,
                  acc[4] * inv + bv1.x, acc[5] * inv + bv1.y,
                  acc[6] * inv + bv1.z, acc[7] * inv + bv1.w};
    if constexpr (sizeof(OUT_T) == 2) {
        bf16x8 ov;
#pragma unroll
        for (int k = 0; k < 8; ++k) ov[k] = (bf16)o[k];
        *(bf16x8*)((bf16*)out + (size_t)d * 128 + gl * 8) = ov;
    } else {
        float* op = (float*)out + (size_t)d * 128 + gl * 8;
        *(float4*)op       = (float4){o[0], o[1], o[2], o[3]};
        *(float4*)(op + 4) = (float4){o[4], o[5], o[6], o[7]};
    }
}

// ---------------- per-graph mean/max pooling (bf16 input; batch_idx sorted) -------
__global__ __launch_bounds__(256)
void pool_kernel(const bf16* __restrict__ out2, const int* __restrict__ batch_idx,
                 float* __restrict__ mean, float* __restrict__ mx) {
    int g = blockIdx.x;
    int j = threadIdx.x & 127;
    int grp = threadIdx.x >> 7;
    int lo = 0, hi = N_NODES;
    while (lo < hi) { int mid = (lo + hi) >> 1; if (batch_idx[mid] < g) lo = mid + 1; else hi = mid; }
    int start = lo;
    hi = N_NODES;
    while (lo < hi) { int mid = (lo + hi) >> 1; if (batch_idx[mid] < g + 1) lo = mid + 1; else hi = mid; }
    int end = lo;

    float s = 0.f, mmax = -INFINITY;
    for (int r = start + grp; r < end; r += 2) {
        float v = (float)out2[(size_t)r * 128 + j];
        s += v;
        mmax = fmaxf(mmax, v);
    }
    __shared__ float ls[2][128], lm[2][128];
    ls[grp][j] = s; lm[grp][j] = mmax;
    __syncthreads();
    if (grp == 0) {
        int cnt = end - start;
        float sum = ls[0][j] + ls[1][j];
        float mv = fmaxf(lm[0][j], lm[1][j]);
        mean[g * 128 + j] = sum / fmaxf((float)cnt, 1.f);
        mx[g * 128 + j] = (cnt > 0) ? mv : 0.f;
    }
}

// ---------------- head ----------------
__global__ __launch_bounds__(128)
void head_kernel(const float* __restrict__ mean, const float* __restrict__ mx,
                 const float* __restrict__ gfeat, const float* __restrict__ Wg,
                 const float* __restrict__ bg, const float* __restrict__ Wo,
                 const float* __restrict__ bo, float* __restrict__ out) {
    int g = blockIdx.x;
    int j = threadIdx.x;
    float gft = bg[j];
#pragma unroll
    for (int k = 0; k < 32; ++k)
        gft += gfeat[g * 32 + k] * Wg[k * 128 + j];
    float mj = mean[g * 128 + j], xj = mx[g * 128 + j];
    float p0 = mj * Wo[j * 2 + 0] + xj * Wo[(128 + j) * 2 + 0] + gft * Wo[(256 + j) * 2 + 0];
    float p1 = mj * Wo[j * 2 + 1] + xj * Wo[(128 + j) * 2 + 1] + gft * Wo[(256 + j) * 2 + 1];
#pragma unroll
    for (int m = 32; m >= 1; m >>= 1) { p0 += __shfl_xor(p0, m); p1 += __shfl_xor(p1, m); }
    __shared__ float l0s[2], l1s[2];
    int wv = j >> 6;
    if ((j & 63) == 0) { l0s[wv] = p0; l1s[wv] = p1; }
    __syncthreads();
    if (j == 0) {
        float l0 = l0s[0] + l0s[1] + bo[0];
        float l1 = l1s[0] + l1s[1] + bo[1];
        float mm = fmaxf(l0, l1);
        float lse = mm + logf(__expf(l0 - mm) + __expf(l1 - mm));
        out[g * 2 + 0] = l0 - lse;
        out[g * 2 + 1] = l1 - lse;
    }
}

extern "C" void kernel_launch(void* const* d_in, const int* in_sizes, int n_in,
                              void* d_out, int out_size, void* d_ws, size_t ws_size,
                              hipStream_t stream) {
    const float* x     = (const float*)d_in[0];
    const int*   edges = (const int*)d_in[1];
    const int*   batch = (const int*)d_in[2];
    const float* gfeat = (const float*)d_in[3];
    const float* W1    = (const float*)d_in[4];
    const float* a1s   = (const float*)d_in[5];
    const float* a1d   = (const float*)d_in[6];
    const float* b1    = (const float*)d_in[7];
    const float* W2    = (const float*)d_in[8];
    const float* a2s   = (const float*)d_in[9];
    const float* a2d   = (const float*)d_in[10];
    const float* b2    = (const float*)d_in[11];
    const float* Wg    = (const float*)d_in[12];
    const float* bg    = (const float*)d_in[13];
    const float* Wo    = (const float*)d_in[14];
    const float* bo    = (const float*)d_in[15];

    char* ws = (char*)d_ws;
    bf16*     WT1       = (bf16*)(ws + 0);          //  65536 B
    bf16*     WT2       = (bf16*)(ws + 65536);      //  32768 B
    float*    s_src     = (float*)(ws + 98304);     // 200704 B
    float*    s_dst     = (float*)(ws + 299008);    // 200704 B
    int*      counts    = (int*)(ws + 499712);      // 200704 B
    int*      blocksums = (int*)(ws + 700416);      // 256 B
    int*      mat       = (int*)(ws + 700672);      // 76832 B
    int*      rowsum    = (int*)(ws + 777536);      // 392 B
    int*      poff      = (int*)(ws + 777984);      // 396 B
    int*      offsets   = (int*)(ws + 778432);      // 200704 B (N+1 ints)
    int*      sorted    = (int*)(ws + 979136);      // 3400704 B
    bf16*     h         = (bf16*)(ws + 4502528);    // 12.8 MB
    bf16*     out1      = (bf16*)(ws + 17302528);   // 12.8 MB
    bf16*     out2      = (bf16*)(ws + 30102528);   // 12.8 MB
    unsigned* pairs     = (unsigned*)(ws + 43002528); // 3.2 MB
    float*    pmean     = (float*)(ws + 55702528);  // 131072 B
    float*    pmax      = (float*)(ws + 55833600);  // 131072 B

    const int* e_src = edges;
    const int* e_dst = edges + N_EDGES;

    // --- W transposes + f32->bf16 cast (single tiny launch) ---
    transpose2_kernel<<<(FIN * EMB + EMB * EMB + 255) / 256, 256, 0, stream>>>(W1, WT1, W2, WT2);

    // --- CSR by dst: fine radix partition (98), single-writer write lines ---
    hipMemsetAsync(counts, 0, N_NODES * sizeof(int), stream);
    hist_part_kernel<<<RBLK, 256, 0, stream>>>(e_dst, counts, mat);
    int nblk = (N_NODES + 1023) / 1024;   // 49
    scan_block_kernel<<<nblk, 1024, 0, stream>>>(counts, offsets, blocksums);
    scan_fix_kernel<<<nblk, 1024, 0, stream>>>(offsets, blocksums, nblk, sorted);
    rowscan_kernel<<<NP, 256, 0, stream>>>(mat, rowsum);
    partbase_kernel<<<1, 128, 0, stream>>>(rowsum, poff);
    radix_scatter_kernel<<<RBLK, 256, 0, stream>>>(e_src, e_dst, mat, poff, pairs);
    bucket_place_kernel<<<NB, 1024, 0, stream>>>(poff, offsets, pairs, sorted);

    int gemm_blocks = (N_NODES + 31) / 32;   // 1563: ~6 blocks/CU for TLP
    int agg_blocks = (N_NODES + 15) / 16;

    // --- layer 1 (scores fused into gemm epilogue) ---
    gemm_kernel<FIN, float><<<gemm_blocks, 256, 0, stream>>>(x, WT1, h, N_NODES,
                                                             a1s, a1d, s_src, s_dst);
    agg_kernel<bf16><<<agg_blocks, 256, 0, stream>>>(offsets, sorted, s_src, s_dst, h, b1, out1);

    // --- layer 2 ---
    gemm_kernel<EMB, bf16><<<gemm_blocks, 256, 0, stream>>>(out1, WT2, h, N_NODES,
                                                            a2s, a2d, s_src, s_dst);
    agg_kernel<bf16><<<agg_blocks, 256, 0, stream>>>(offsets, sorted, s_src, s_dst, h, b2, out2);

    // --- pooling + head ---
    pool_kernel<<<NGRAPH, 256, 0, stream>>>(out2, batch, pmean, pmax);
    head_kernel<<<NGRAPH, 128, 0, stream>>>(pmean, pmax, gfeat, Wg, bg, Wo, bo, (float*)d_out);
}

// Round 16
// 175.479 us; speedup vs baseline: 1.4267x; 1.2190x over previous
//
#include <hip/hip_runtime.h>
#include <hip/hip_bf16.h>

#define N_NODES 50000
#define N_EDGES 800000
#define FIN 256
#define EMB 128
#define NGRAPH 256
#define TOT_E (N_EDGES + N_NODES)
#define NP 98              // partitions of 512 dst nodes (d >> 9)
#define RBLK 196           // radix blocks; 196 * 4096 edges >= 800000

typedef __bf16 bf16;
typedef __attribute__((ext_vector_type(8))) __bf16 bf16x8;
typedef __attribute__((ext_vector_type(4))) __bf16 bf16x4;
typedef __attribute__((ext_vector_type(2))) __bf16 bf16x2;
typedef __attribute__((ext_vector_type(4))) float f32x4;
typedef __attribute__((ext_vector_type(4))) int i32x4;

// ---------------- both W transposes + f32->bf16 cast in one launch ----------------
__global__ void transpose2_kernel(const float* __restrict__ W1, bf16* __restrict__ WT1,
                                  const float* __restrict__ W2, bf16* __restrict__ WT2) {
    int t = blockIdx.x * 256 + threadIdx.x;
    if (t < FIN * EMB) {                       // WT1[c][r] = W1[r][c], r<256, c<128
        int c = t / FIN, r = t - c * FIN;
        WT1[t] = (bf16)W1[r * EMB + c];
    } else if (t < FIN * EMB + EMB * EMB) {    // WT2
        int u = t - FIN * EMB;
        int c = u / EMB, r = u - c * EMB;
        WT2[u] = (bf16)W2[r * EMB + c];
    }
}

// ---------------- CSR build, round-16: radix + partition-local offsets ------------
// r12-r15 confirmed: single-writer-per-line write amp ~1. Now the offsets scan is
// partition-local: after radix partitioning, partition p's CSR base is exactly
// poff[p] + p*512 (edges-before + self-loops-before), so counts[] global atomics,
// scan_block and scan_fix are all dead. part_build does LDS hist+scan+place.

// Per-block partition histogram only (mat[NP][RBLK]); no global counts.
__global__ __launch_bounds__(256)
void hist_part_kernel(const int* __restrict__ e_dst, int* __restrict__ mat) {
    __shared__ int lh[NP];
    int t = threadIdx.x;
    for (int k = t; k < NP; k += 256) lh[k] = 0;
    __syncthreads();
    const int NQ = N_EDGES / 4;
    int base = blockIdx.x * 1024;
#pragma unroll
    for (int j = 0; j < 4; ++j) {
        int i = base + j * 256 + t;
        if (i < NQ) {
            i32x4 d4 = *(const i32x4*)(e_dst + 4 * i);
#pragma unroll
            for (int k = 0; k < 4; ++k) atomicAdd(&lh[d4[k] >> 9], 1);
        }
    }
    __syncthreads();
    for (int k = t; k < NP; k += 256) mat[k * RBLK + blockIdx.x] = lh[k];
}

// Coalesced per-row exclusive scan of mat[NP][RBLK]; rowsum[p] = row total.
__global__ __launch_bounds__(256)
void rowscan_kernel(int* __restrict__ mat, int* __restrict__ rowsum) {
    __shared__ int lds[256];
    int p = blockIdx.x, t = threadIdx.x;
    int v = (t < RBLK) ? mat[p * RBLK + t] : 0;
    lds[t] = v;
    __syncthreads();
    for (int d = 1; d < 256; d <<= 1) {
        int u = (t >= d) ? lds[t - d] : 0;
        __syncthreads();
        lds[t] += u;
        __syncthreads();
    }
    if (t < RBLK) mat[p * RBLK + t] = lds[t] - v;
    if (t == 255) rowsum[p] = lds[255];
}

// Tiny scan of the 98 row sums -> partition bases poff[NP+1].
__global__ __launch_bounds__(128)
void partbase_kernel(const int* __restrict__ rowsum, int* __restrict__ poff) {
    __shared__ int lds[128];
    int t = threadIdx.x;
    int v = (t < NP) ? rowsum[t] : 0;
    lds[t] = v;
    __syncthreads();
    for (int d = 1; d < 128; d <<= 1) {
        int u = (t >= d) ? lds[t - d] : 0;
        __syncthreads();
        lds[t] += u;
        __syncthreads();
    }
    if (t < NP) poff[t] = lds[t] - v;
    if (t == 0) poff[NP] = N_EDGES;
}

// Radix place: block's writes go to its NP PRIVATE sub-ranges (single-writer).
__global__ __launch_bounds__(256)
void radix_scatter_kernel(const int* __restrict__ e_src, const int* __restrict__ e_dst,
                          const int* __restrict__ mat, const int* __restrict__ poff,
                          unsigned* __restrict__ pairs) {
    __shared__ int cur[NP];
    int t = threadIdx.x;
    for (int k = t; k < NP; k += 256) cur[k] = poff[k] + mat[k * RBLK + blockIdx.x];
    __syncthreads();
    const int NQ = N_EDGES / 4;
    int base = blockIdx.x * 1024;
#pragma unroll
    for (int j = 0; j < 4; ++j) {
        int i = base + j * 256 + t;
        if (i < NQ) {
            i32x4 d4 = *(const i32x4*)(e_dst + 4 * i);
            i32x4 s4 = *(const i32x4*)(e_src + 4 * i);
#pragma unroll
            for (int k = 0; k < 4; ++k) {
                int d = d4[k];
                int pos = atomicAdd(&cur[d >> 9], 1);
                pairs[pos] = ((unsigned)d << 16) | (unsigned)s4[k];   // d,s < 2^16
            }
        }
    }
}

// One block per 512-node partition: LDS hist of own pairs segment (L2-resident),
// LDS scan -> offsets (+self-loop seed) -> place. All writes in the partition's
// private contiguous region; no global atomics anywhere.
__global__ __launch_bounds__(1024)
void part_build_kernel(const int* __restrict__ poff, const unsigned* __restrict__ pairs,
                       int* __restrict__ offsets, int* __restrict__ sorted) {
    int p = blockIdx.x, t = threadIdx.x;
    int nbase = p * 512;
    int valid = N_NODES - nbase;
    valid = valid > 512 ? 512 : valid;           // 512, except 336 for p=97
    __shared__ int cnt[512], sc[512];
    if (t < 512) cnt[t] = (t < valid) ? 1 : 0;   // self-loop
    __syncthreads();
    int p0 = poff[p], p1 = poff[p + 1];
    for (int i = p0 + t; i < p1; i += 1024)
        atomicAdd(&cnt[(pairs[i] >> 16) & 511], 1);
    __syncthreads();
    int v = (t < 512) ? cnt[t] : 0;
    if (t < 512) sc[t] = v;
    __syncthreads();
    for (int d = 1; d < 512; d <<= 1) {          // Hillis-Steele inclusive
        int u = (t < 512 && t >= d) ? sc[t - d] : 0;
        __syncthreads();
        if (t < 512) sc[t] += u;
        __syncthreads();
    }
    int base = p0 + nbase;                       // edges-before + selfloops-before
    if (t < valid) {
        int off = base + (sc[t] - v);            // exclusive
        offsets[nbase + t] = off;
        sorted[off] = nbase + t;                 // self-loop at slot 0
        cnt[t] = off + 1;                        // global cursor
    }
    if (p == 0 && t == 0) offsets[N_NODES] = TOT_E;
    __syncthreads();
    for (int i = p0 + t; i < p1; i += 1024) {
        unsigned pr = pairs[i];
        int pos = atomicAdd(&cnt[(pr >> 16) & 511], 1);
        sorted[pos] = (int)(pr & 0xFFFFu);
    }
}

// ---------------- GEMM + fused scores (r15 structure: LDS, BK=64, swizzle, 32-row)
template<int K, typename AT>
__global__ __launch_bounds__(256)
void gemm_kernel(const AT* __restrict__ A, const bf16* __restrict__ WT,
                 bf16* __restrict__ C, int M,
                 const float* __restrict__ a_src, const float* __restrict__ a_dst,
                 float* __restrict__ s_src, float* __restrict__ s_dst) {
    __shared__ __align__(16) bf16 As[32][64];    //  4 KB
    __shared__ __align__(16) bf16 Bs[128][64];   // 16 KB
    __shared__ float sbuf[2][32];
    int tid = threadIdx.x;
    int wave = tid >> 6, lane = tid & 63;
    int rowHalf = wave & 1, colHalf = wave >> 1;
    int m0 = blockIdx.x * 32;

    f32x4 acc[4];
#pragma unroll
    for (int i = 0; i < 4; ++i) acc[i] = (f32x4){0.f, 0.f, 0.f, 0.f};

    for (int k0 = 0; k0 < K; k0 += 64) {
        if constexpr (sizeof(AT) == 4) {
#pragma unroll
            for (int it = 0; it < 2; ++it) {               // 32 rows x 16 seg4
                int task = tid + it * 256;
                int row = task >> 4, seg4 = task & 15;
                int gr = m0 + row;
                float4 f = make_float4(0.f, 0.f, 0.f, 0.f);
                if (gr < M) f = *(const float4*)((const float*)A + (size_t)gr * K + k0 + seg4 * 4);
                bf16x4 b4 = (bf16x4){(bf16)f.x, (bf16)f.y, (bf16)f.z, (bf16)f.w};
                int slot = seg4 >> 1, half8 = seg4 & 1;
                int ss = slot ^ (row & 7);
                *(bf16x4*)(&As[row][ss * 8 + half8 * 4]) = b4;
            }
        } else {
            int row = tid >> 3, slot = tid & 7;            // 32 rows x 8 slots
            int gr = m0 + row;
            uint4 v = make_uint4(0u, 0u, 0u, 0u);
            if (gr < M) v = *(const uint4*)((const bf16*)A + (size_t)gr * K + k0 + slot * 8);
            int ss = slot ^ (row & 7);
            *(uint4*)(&As[row][ss * 8]) = v;
        }
#pragma unroll
        for (int it = 0; it < 4; ++it) {                   // 128 cols x 8 slots
            int task = tid + it * 256;
            int col = task >> 3, slot = task & 7;
            uint4 v = *(const uint4*)(WT + (size_t)col * K + k0 + slot * 8);
            int ss = slot ^ (col & 7);
            *(uint4*)(&Bs[col][ss * 8]) = v;
        }
        __syncthreads();
        int tr = rowHalf * 16 + (lane & 15);
        int kseg = lane >> 4;                              // 0..3
        bf16x8 af0 = *(const bf16x8*)(&As[tr][((kseg) ^ (tr & 7)) * 8]);
        bf16x8 af1 = *(const bf16x8*)(&As[tr][((4 + kseg) ^ (tr & 7)) * 8]);
#pragma unroll
        for (int n = 0; n < 4; ++n) {
            int c = colHalf * 64 + n * 16 + (lane & 15);
            bf16x8 b0 = *(const bf16x8*)(&Bs[c][((kseg) ^ (c & 7)) * 8]);
            bf16x8 b1 = *(const bf16x8*)(&Bs[c][((4 + kseg) ^ (c & 7)) * 8]);
            acc[n] = __builtin_amdgcn_mfma_f32_16x16x32_bf16(af0, b0, acc[n], 0, 0, 0);
            acc[n] = __builtin_amdgcn_mfma_f32_16x16x32_bf16(af1, b1, acc[n], 0, 0, 0);
        }
        __syncthreads();
    }
    int rbase = m0 + rowHalf * 16 + ((lane >> 4) << 2);
    int cb = lane & 15;
#pragma unroll
    for (int n = 0; n < 4; ++n) {
        int col = colHalf * 64 + n * 16 + cb;
#pragma unroll
        for (int rr = 0; rr < 4; ++rr) {
            int row = rbase + rr;
            if (row < M) C[(size_t)row * 128 + col] = (bf16)acc[n][rr];
        }
    }
    // fused scores epilogue (cross col-half combine via LDS)
    if (tid < 64) sbuf[tid >> 5][tid & 31] = 0.f;
    __syncthreads();
    float a_s[4], a_d[4];
#pragma unroll
    for (int n = 0; n < 4; ++n) {
        a_s[n] = a_src[colHalf * 64 + n * 16 + cb];
        a_d[n] = a_dst[colHalf * 64 + n * 16 + cb];
    }
#pragma unroll
    for (int rr = 0; rr < 4; ++rr) {
        float ps = 0.f, pd = 0.f;
#pragma unroll
        for (int n = 0; n < 4; ++n) {
            ps += acc[n][rr] * a_s[n];
            pd += acc[n][rr] * a_d[n];
        }
#pragma unroll
        for (int mk = 8; mk >= 1; mk >>= 1) {
            ps += __shfl_xor(ps, mk);
            pd += __shfl_xor(pd, mk);
        }
        if (cb == 0) {
            int tr16 = rowHalf * 16 + (lane >> 4) * 4 + rr;
            atomicAdd(&sbuf[0][tr16], ps);
            atomicAdd(&sbuf[1][tr16], pd);
        }
    }
    __syncthreads();
    if (tid < 32 && m0 + tid < M) {
        s_src[m0 + tid] = sbuf[0][tid];
        s_dst[m0 + tid] = sbuf[1][tid];
    }
}

// ---------------- per-node softmax-aggregate (16-lane groups, 4 nodes/wave) ----------------
template<typename OUT_T>
__global__ __launch_bounds__(256)
void agg_kernel(const int* __restrict__ offsets, const int* __restrict__ sorted_src,
                const float* __restrict__ s_src, const float* __restrict__ s_dst,
                const bf16* __restrict__ h, const float* __restrict__ bias,
                OUT_T* __restrict__ out) {
    int tid = threadIdx.x;
    int wave = tid >> 6, lane = tid & 63;
    int gl = lane & 15;
    int gbase = lane & 48;
    int d = blockIdx.x * 16 + wave * 4 + (lane >> 4);
    if (d >= N_NODES) return;
    int r0 = offsets[d];
    int deg = offsets[d + 1] - r0;
    float sd = s_dst[d];

    int sv0 = 0, sv1 = 0;
    float ev0 = -INFINITY, ev1 = -INFINITY;
    if (gl < deg) {
        sv0 = sorted_src[r0 + gl];
        float e = s_src[sv0] + sd;
        ev0 = (e > 0.f) ? e : 0.2f * e;
    }
    if (16 + gl < deg) {
        sv1 = sorted_src[r0 + 16 + gl];
        float e = s_src[sv1] + sd;
        ev1 = (e > 0.f) ? e : 0.2f * e;
    }
    float m = fmaxf(ev0, ev1);
    for (int i = 32 + gl; i < deg; i += 16) {
        int s = sorted_src[r0 + i];
        float e = s_src[s] + sd;
        e = (e > 0.f) ? e : 0.2f * e;
        m = fmaxf(m, e);
    }
#pragma unroll
    for (int mk = 8; mk >= 1; mk >>= 1) m = fmaxf(m, __shfl_xor(m, mk));

    float pv0 = (gl < deg) ? __expf(ev0 - m) : 0.f;
    float pv1 = (16 + gl < deg) ? __expf(ev1 - m) : 0.f;
    float den = pv0 + pv1;
    for (int i = 32 + gl; i < deg; i += 16) {
        int s = sorted_src[r0 + i];
        float e = s_src[s] + sd;
        e = (e > 0.f) ? e : 0.2f * e;
        den += __expf(e - m);
    }
#pragma unroll
    for (int mk = 8; mk >= 1; mk >>= 1) den += __shfl_xor(den, mk);

    float acc[8];
#pragma unroll
    for (int k = 0; k < 8; ++k) acc[k] = 0.f;

    int jm = (deg < 32) ? deg : 32;
#pragma unroll 8
    for (int j = 0; j < jm; ++j) {
        int src_lane = gbase + (j & 15);
        int s = __shfl((j < 16) ? sv0 : sv1, src_lane);
        float p = __shfl((j < 16) ? pv0 : pv1, src_lane);
        bf16x8 hv = *(const bf16x8*)(h + (size_t)s * 128 + gl * 8);
#pragma unroll
        for (int k = 0; k < 8; ++k) acc[k] += p * (float)hv[k];
    }
    for (int i = 32; i < deg; ++i) {
        int s = sorted_src[r0 + i];
        float e = s_src[s] + sd;
        e = (e > 0.f) ? e : 0.2f * e;
        float p = __expf(e - m);
        bf16x8 hv = *(const bf16x8*)(h + (size_t)s * 128 + gl * 8);
#pragma unroll
        for (int k = 0; k < 8; ++k) acc[k] += p * (float)hv[k];
    }

    float inv = 1.f / den;
    float4 bv0 = *(const float4*)(bias + gl * 8);
    float4 bv1 = *(const float4*)(bias + gl * 8 + 4);
    float o[8] = {acc[0] * inv + bv0.x, acc[1] * inv + bv0.y,
                  acc[2] * inv + bv0.z, acc[3] * inv + bv0.w,
                  acc[4] * inv + bv1.x, acc[5] * inv + bv1.y,
                  acc[6] * inv + bv1.z, acc[7] * inv + bv1.w};
    if constexpr (sizeof(OUT_T) == 2) {
        bf16x8 ov;
#pragma unroll
        for (int k = 0; k < 8; ++k) ov[k] = (bf16)o[k];
        *(bf16x8*)((bf16*)out + (size_t)d * 128 + gl * 8) = ov;
    } else {
        float* op = (float*)out + (size_t)d * 128 + gl * 8;
        *(float4*)op       = (float4){o[0], o[1], o[2], o[3]};
        *(float4*)(op + 4) = (float4){o[4], o[5], o[6], o[7]};
    }
}

// ---------------- per-graph mean/max pooling (bf16 input; batch_idx sorted) -------
__global__ __launch_bounds__(256)
void pool_kernel(const bf16* __restrict__ out2, const int* __restrict__ batch_idx,
                 float* __restrict__ mean, float* __restrict__ mx) {
    int g = blockIdx.x;
    int j = threadIdx.x & 127;
    int grp = threadIdx.x >> 7;
    int lo = 0, hi = N_NODES;
    while (lo < hi) { int mid = (lo + hi) >> 1; if (batch_idx[mid] < g) lo = mid + 1; else hi = mid; }
    int start = lo;
    hi = N_NODES;
    while (lo < hi) { int mid = (lo + hi) >> 1; if (batch_idx[mid] < g + 1) lo = mid + 1; else hi = mid; }
    int end = lo;

    float s = 0.f, mmax = -INFINITY;
    for (int r = start + grp; r < end; r += 2) {
        float v = (float)out2[(size_t)r * 128 + j];
        s += v;
        mmax = fmaxf(mmax, v);
    }
    __shared__ float ls[2][128], lm[2][128];
    ls[grp][j] = s; lm[grp][j] = mmax;
    __syncthreads();
    if (grp == 0) {
        int cnt = end - start;
        float sum = ls[0][j] + ls[1][j];
        float mv = fmaxf(lm[0][j], lm[1][j]);
        mean[g * 128 + j] = sum / fmaxf((float)cnt, 1.f);
        mx[g * 128 + j] = (cnt > 0) ? mv : 0.f;
    }
}

// ---------------- head ----------------
__global__ __launch_bounds__(128)
void head_kernel(const float* __restrict__ mean, const float* __restrict__ mx,
                 const float* __restrict__ gfeat, const float* __restrict__ Wg,
                 const float* __restrict__ bg, const float* __restrict__ Wo,
                 const float* __restrict__ bo, float* __restrict__ out) {
    int g = blockIdx.x;
    int j = threadIdx.x;
    float gft = bg[j];
#pragma unroll
    for (int k = 0; k < 32; ++k)
        gft += gfeat[g * 32 + k] * Wg[k * 128 + j];
    float mj = mean[g * 128 + j], xj = mx[g * 128 + j];
    float p0 = mj * Wo[j * 2 + 0] + xj * Wo[(128 + j) * 2 + 0] + gft * Wo[(256 + j) * 2 + 0];
    float p1 = mj * Wo[j * 2 + 1] + xj * Wo[(128 + j) * 2 + 1] + gft * Wo[(256 + j) * 2 + 1];
#pragma unroll
    for (int m = 32; m >= 1; m >>= 1) { p0 += __shfl_xor(p0, m); p1 += __shfl_xor(p1, m); }
    __shared__ float l0s[2], l1s[2];
    int wv = j >> 6;
    if ((j & 63) == 0) { l0s[wv] = p0; l1s[wv] = p1; }
    __syncthreads();
    if (j == 0) {
        float l0 = l0s[0] + l0s[1] + bo[0];
        float l1 = l1s[0] + l1s[1] + bo[1];
        float mm = fmaxf(l0, l1);
        float lse = mm + logf(__expf(l0 - mm) + __expf(l1 - mm));
        out[g * 2 + 0] = l0 - lse;
        out[g * 2 + 1] = l1 - lse;
    }
}

extern "C" void kernel_launch(void* const* d_in, const int* in_sizes, int n_in,
                              void* d_out, int out_size, void* d_ws, size_t ws_size,
                              hipStream_t stream) {
    const float* x     = (const float*)d_in[0];
    const int*   edges = (const int*)d_in[1];
    const int*   batch = (const int*)d_in[2];
    const float* gfeat = (const float*)d_in[3];
    const float* W1    = (const float*)d_in[4];
    const float* a1s   = (const float*)d_in[5];
    const float* a1d   = (const float*)d_in[6];
    const float* b1    = (const float*)d_in[7];
    const float* W2    = (const float*)d_in[8];
    const float* a2s   = (const float*)d_in[9];
    const float* a2d   = (const float*)d_in[10];
    const float* b2    = (const float*)d_in[11];
    const float* Wg    = (const float*)d_in[12];
    const float* bg    = (const float*)d_in[13];
    const float* Wo    = (const float*)d_in[14];
    const float* bo    = (const float*)d_in[15];

    char* ws = (char*)d_ws;
    bf16*     WT1       = (bf16*)(ws + 0);          //  65536 B
    bf16*     WT2       = (bf16*)(ws + 65536);      //  32768 B
    float*    s_src     = (float*)(ws + 98304);     // 200704 B
    float*    s_dst     = (float*)(ws + 299008);    // 200704 B
    int*      mat       = (int*)(ws + 700672);      // 76832 B
    int*      rowsum    = (int*)(ws + 777536);      // 392 B
    int*      poff      = (int*)(ws + 777984);      // 396 B
    int*      offsets   = (int*)(ws + 778432);      // 200704 B (N+1 ints)
    int*      sorted    = (int*)(ws + 979136);      // 3400704 B
    bf16*     h         = (bf16*)(ws + 4502528);    // 12.8 MB
    bf16*     out1      = (bf16*)(ws + 17302528);   // 12.8 MB
    bf16*     out2      = (bf16*)(ws + 30102528);   // 12.8 MB
    unsigned* pairs     = (unsigned*)(ws + 43002528); // 3.2 MB
    float*    pmean     = (float*)(ws + 55702528);  // 131072 B
    float*    pmax      = (float*)(ws + 55833600);  // 131072 B

    const int* e_src = edges;
    const int* e_dst = edges + N_EDGES;

    // --- W transposes + f32->bf16 cast (single tiny launch) ---
    transpose2_kernel<<<(FIN * EMB + EMB * EMB + 255) / 256, 256, 0, stream>>>(W1, WT1, W2, WT2);

    // --- CSR by dst: radix partition + partition-local offsets/placement ---
    hist_part_kernel<<<RBLK, 256, 0, stream>>>(e_dst, mat);
    rowscan_kernel<<<NP, 256, 0, stream>>>(mat, rowsum);
    partbase_kernel<<<1, 128, 0, stream>>>(rowsum, poff);
    radix_scatter_kernel<<<RBLK, 256, 0, stream>>>(e_src, e_dst, mat, poff, pairs);
    part_build_kernel<<<NP, 1024, 0, stream>>>(poff, pairs, offsets, sorted);

    int gemm_blocks = (N_NODES + 31) / 32;   // 1563
    int agg_blocks = (N_NODES + 15) / 16;

    // --- layer 1 (scores fused into gemm epilogue) ---
    gemm_kernel<FIN, float><<<gemm_blocks, 256, 0, stream>>>(x, WT1, h, N_NODES,
                                                             a1s, a1d, s_src, s_dst);
    agg_kernel<bf16><<<agg_blocks, 256, 0, stream>>>(offsets, sorted, s_src, s_dst, h, b1, out1);

    // --- layer 2 ---
    gemm_kernel<EMB, bf16><<<gemm_blocks, 256, 0, stream>>>(out1, WT2, h, N_NODES,
                                                            a2s, a2d, s_src, s_dst);
    agg_kernel<bf16><<<agg_blocks, 256, 0, stream>>>(offsets, sorted, s_src, s_dst, h, b2, out2);

    // --- pooling + head ---
    pool_kernel<<<NGRAPH, 256, 0, stream>>>(out2, batch, pmean, pmax);
    head_kernel<<<NGRAPH, 128, 0, stream>>>(pmean, pmax, gfeat, Wg, bg, Wo, bo, (float*)d_out);
}